// Round 4
// baseline (237.079 us; speedup 1.0000x reference)
//
#include <hip/hip_runtime.h>

#define B_  32
#define CL_ 1024
#define QL_ 256
#define D_  768

typedef _Float16 f16x8 __attribute__((ext_vector_type(8)));
typedef float    f32x4 __attribute__((ext_vector_type(4)));

// ---------------- rowdot: out[row] = dot(X[row,:], w[:]) over D=768 ----------------
__global__ void rowdot_kernel(const float* __restrict__ X, const float* __restrict__ w,
                              float* __restrict__ out) {
    int wave = threadIdx.x >> 6;
    int lane = threadIdx.x & 63;
    int row  = blockIdx.x * 4 + wave;
    const float* x = X + (size_t)row * D_;
    float s = 0.f;
#pragma unroll
    for (int k = 0; k < D_ / 64; ++k) s += x[lane + k * 64] * w[lane + k * 64];
#pragma unroll
    for (int m = 32; m; m >>= 1) s += __shfl_xor(s, m, 64);
    if (lane == 0) out[row] = s;
}

// ---------------- prep Q: QT[b][d][j] f16 and Qh[b][j][d] f16 (vectorized) ----------------
__global__ __launch_bounds__(256) void prep_q_kernel(const float* __restrict__ Q,
                                                     _Float16* __restrict__ QT,
                                                     _Float16* __restrict__ Qh) {
    __shared__ float tile[64][65];
    int b  = blockIdx.z;
    int j0 = blockIdx.x * 64;
    int d0 = blockIdx.y * 64;
    int t  = threadIdx.x;
    int jj = t >> 4;          // 0..15
    int dd = (t & 15) * 4;    // 0..60
#pragma unroll
    for (int p = 0; p < 4; ++p) {
        int j = jj + p * 16;
        f32x4 v = *(const f32x4*)(Q + ((size_t)b * QL_ + j0 + j) * D_ + d0 + dd);
        *(f32x4*)&tile[j][dd] = v;
        _Float16 h[4] = {(_Float16)v[0], (_Float16)v[1], (_Float16)v[2], (_Float16)v[3]};
        *(uint2*)(Qh + ((size_t)b * QL_ + j0 + j) * D_ + d0 + dd) = *(uint2*)h;
    }
    __syncthreads();
    int j4 = (t & 15) * 4;
#pragma unroll
    for (int p = 0; p < 4; ++p) {
        int d = jj + p * 16;
        _Float16 h[4];
#pragma unroll
        for (int e = 0; e < 4; ++e) h[e] = (_Float16)tile[j4 + e][d];
        *(uint2*)(QT + ((size_t)b * D_ + d0 + d) * QL_ + j0 + j4) = *(uint2*)h;
    }
}

// ---- fused: S-GEMM (128 x 256) + cw1 + row softmax -> S1h + col partial stats ----
__global__ __launch_bounds__(512, 2) void fused_s_kernel(
    const float* __restrict__ C, const _Float16* __restrict__ Qh,
    const float* __restrict__ w, const float* __restrict__ qw2g,
    const int* __restrict__ c_mask, const int* __restrict__ q_mask,
    _Float16* __restrict__ S1h, float* __restrict__ pmg,
    float* __restrict__ psg, float* __restrict__ pumg) {
    __shared__ __align__(16) _Float16 As[128 * 64];
    __shared__ __align__(16) _Float16 Bs[256 * 64];
    __shared__ float w1s[D_], w3s[D_];
    __shared__ float cw1s[128];
    __shared__ float rowredM[512], rowredS[512];
    __shared__ int   cms[128], qms[256];

    int t = threadIdx.x;
    int slice = blockIdx.x;      // 0..7
    int b = blockIdx.y;
    int i0 = slice * 128;
    int wave = t >> 6, lane = t & 63, lrow = lane & 15, lk = lane >> 4;
    int wr = wave >> 2, wc = wave & 3;
    int jw = wc * 64;

    for (int k = t; k < D_; k += 512) { w1s[k] = w[k]; w3s[k] = w[2 * D_ + k]; }
    if (t < 128) cms[t] = c_mask[b * CL_ + i0 + t];
    if (t < 256) qms[t] = q_mask[b * QL_ + t];

    const float* Cbase = C + ((size_t)b * CL_ + i0) * D_;
    const _Float16* Qbase = Qh + (size_t)b * QL_ * D_;

    f32x4 acc[4][4] = {};
    float cwp0 = 0.f, cwp1 = 0.f;
    int arow0 = t >> 3, arow1 = 64 + (t >> 3);
    int asc = t & 7;

    for (int k0 = 0; k0 < D_; k0 += 64) {
        __syncthreads();
        {
            int kk0 = k0 + asc * 8;
            float4 w30 = *(const float4*)(&w3s[kk0]);
            float4 w31 = *(const float4*)(&w3s[kk0 + 4]);
            float4 w10 = *(const float4*)(&w1s[kk0]);
            float4 w11 = *(const float4*)(&w1s[kk0 + 4]);
            const float* src0 = Cbase + (size_t)arow0 * D_ + kk0;
            float4 a0 = *(const float4*)src0;
            float4 a1 = *(const float4*)(src0 + 4);
            f16x8 ah;
            ah[0] = (_Float16)(a0.x * w30.x); ah[1] = (_Float16)(a0.y * w30.y);
            ah[2] = (_Float16)(a0.z * w30.z); ah[3] = (_Float16)(a0.w * w30.w);
            ah[4] = (_Float16)(a1.x * w31.x); ah[5] = (_Float16)(a1.y * w31.y);
            ah[6] = (_Float16)(a1.z * w31.z); ah[7] = (_Float16)(a1.w * w31.w);
            cwp0 += a0.x * w10.x + a0.y * w10.y + a0.z * w10.z + a0.w * w10.w
                  + a1.x * w11.x + a1.y * w11.y + a1.z * w11.z + a1.w * w11.w;
            *(f16x8*)&As[arow0 * 64 + ((asc ^ (arow0 & 7)) * 8)] = ah;
            const float* src1 = Cbase + (size_t)arow1 * D_ + kk0;
            float4 b0 = *(const float4*)src1;
            float4 b1 = *(const float4*)(src1 + 4);
            f16x8 bh;
            bh[0] = (_Float16)(b0.x * w30.x); bh[1] = (_Float16)(b0.y * w30.y);
            bh[2] = (_Float16)(b0.z * w30.z); bh[3] = (_Float16)(b0.w * w30.w);
            bh[4] = (_Float16)(b1.x * w31.x); bh[5] = (_Float16)(b1.y * w31.y);
            bh[6] = (_Float16)(b1.z * w31.z); bh[7] = (_Float16)(b1.w * w31.w);
            cwp1 += b0.x * w10.x + b0.y * w10.y + b0.z * w10.z + b0.w * w10.w
                  + b1.x * w11.x + b1.y * w11.y + b1.z * w11.z + b1.w * w11.w;
            *(f16x8*)&As[arow1 * 64 + ((asc ^ (arow1 & 7)) * 8)] = bh;
        }
#pragma unroll
        for (int sb = 0; sb < 4; ++sb) {
            int row = sb * 64 + (t >> 3);
            f16x8 bh = *(const f16x8*)(Qbase + (size_t)row * D_ + k0 + asc * 8);
            *(f16x8*)&Bs[row * 64 + ((asc ^ (row & 7)) * 8)] = bh;
        }
        __syncthreads();
#pragma unroll
        for (int kk = 0; kk < 2; ++kk) {
            int slot = kk * 4 + lk;
            int swa = (slot ^ (lrow & 7)) * 8;
            f16x8 af[4];
#pragma unroll
            for (int m = 0; m < 4; ++m)
                af[m] = *(const f16x8*)&As[(wr * 64 + m * 16 + lrow) * 64 + swa];
#pragma unroll
            for (int n = 0; n < 4; ++n) {
                int rb = jw + n * 16 + lrow;
                f16x8 bf = *(const f16x8*)&Bs[rb * 64 + swa];
#pragma unroll
                for (int m = 0; m < 4; ++m)
                    acc[m][n] = __builtin_amdgcn_mfma_f32_16x16x32_f16(af[m], bf, acc[m][n], 0, 0, 0);
            }
        }
    }

    // ---- cw1 reduction ----
    cwp0 += __shfl_xor(cwp0, 1, 64); cwp0 += __shfl_xor(cwp0, 2, 64); cwp0 += __shfl_xor(cwp0, 4, 64);
    cwp1 += __shfl_xor(cwp1, 1, 64); cwp1 += __shfl_xor(cwp1, 2, 64); cwp1 += __shfl_xor(cwp1, 4, 64);
    if ((t & 7) == 0) { cw1s[arow0] = cwp0; cw1s[arow1] = cwp1; }
    __syncthreads();

    // ---- S = clip(acc + cw1 + qw2) ----
    float qwv[4]; int qmv[4];
#pragma unroll
    for (int n = 0; n < 4; ++n) {
        int j = jw + n * 16 + lrow;
        qwv[n] = qw2g[b * QL_ + j];
        qmv[n] = qms[j];
    }
#pragma unroll
    for (int m = 0; m < 4; ++m) {
#pragma unroll
        for (int r = 0; r < 4; ++r) {
            float cw = cw1s[wr * 64 + m * 16 + lk * 4 + r];
#pragma unroll
            for (int n = 0; n < 4; ++n) {
                float v = acc[m][n][r] + cw + qwv[n];
                acc[m][n][r] = fminf(15.f, fmaxf(-15.f, v));
            }
        }
    }

    // ---- column partial stats ----
    {
        float pmv[4], psv[4], pumv[4];
#pragma unroll
        for (int n = 0; n < 4; ++n) {
            float pmax = -1e30f, umax = -1e30f;
#pragma unroll
            for (int m = 0; m < 4; ++m)
#pragma unroll
                for (int r = 0; r < 4; ++r) {
                    int cm = cms[wr * 64 + m * 16 + lk * 4 + r];
                    float v = acc[m][n][r];
                    pmax = fmaxf(pmax, cm ? v : 0.0f);
                    umax = fmaxf(umax, cm ? v : -1e30f);
                }
            float s = 0.f;
#pragma unroll
            for (int m = 0; m < 4; ++m)
#pragma unroll
                for (int r = 0; r < 4; ++r) {
                    int cm = cms[wr * 64 + m * 16 + lk * 4 + r];
                    s += cm ? __expf(acc[m][n][r] - pmax) : 0.0f;
                }
            pmv[n] = pmax; psv[n] = s; pumv[n] = umax;
        }
#pragma unroll
        for (int off = 16; off <= 32; off <<= 1) {
#pragma unroll
            for (int n = 0; n < 4; ++n) {
                float om = __shfl_xor(pmv[n], off, 64);
                float os = __shfl_xor(psv[n], off, 64);
                float ou = __shfl_xor(pumv[n], off, 64);
                float nm = fmaxf(pmv[n], om);
                psv[n] = psv[n] * __expf(pmv[n] - nm) + os * __expf(om - nm);
                pmv[n] = nm;
                pumv[n] = fmaxf(pumv[n], ou);
            }
        }
        if (lk == 0) {
#pragma unroll
            for (int n = 0; n < 4; ++n) {
                int idx = (b * 16 + slice * 2 + wr) * QL_ + jw + n * 16 + lrow;
                pmg[idx] = pmv[n]; psg[idx] = psv[n]; pumg[idx] = pumv[n];
            }
        }
    }

    // ---- row softmax ----
    float Mv[4][4];
#pragma unroll
    for (int m = 0; m < 4; ++m)
#pragma unroll
        for (int r = 0; r < 4; ++r) {
            float lm = qmv[0] ? acc[m][0][r] : 0.0f;
#pragma unroll
            for (int n = 1; n < 4; ++n) lm = fmaxf(lm, qmv[n] ? acc[m][n][r] : 0.0f);
            lm = fmaxf(lm, __shfl_xor(lm, 1, 64));
            lm = fmaxf(lm, __shfl_xor(lm, 2, 64));
            lm = fmaxf(lm, __shfl_xor(lm, 4, 64));
            lm = fmaxf(lm, __shfl_xor(lm, 8, 64));
            Mv[m][r] = lm;
        }
    if (lrow == 0) {
#pragma unroll
        for (int m = 0; m < 4; ++m)
#pragma unroll
            for (int r = 0; r < 4; ++r)
                rowredM[wave * 64 + m * 16 + lk * 4 + r] = Mv[m][r];
    }
    __syncthreads();
#pragma unroll
    for (int m = 0; m < 4; ++m)
#pragma unroll
        for (int r = 0; r < 4; ++r) {
            int row = wr * 256 + m * 16 + lk * 4 + r;
            Mv[m][r] = fmaxf(fmaxf(rowredM[row], rowredM[64 + row]),
                             fmaxf(rowredM[128 + row], rowredM[192 + row]));
        }
    float inv_[4][4];
#pragma unroll
    for (int m = 0; m < 4; ++m)
#pragma unroll
        for (int r = 0; r < 4; ++r) {
            float ls = 0.f;
#pragma unroll
            for (int n = 0; n < 4; ++n) {
                float e = qmv[n] ? __expf(acc[m][n][r] - Mv[m][r]) : 0.0f;
                acc[m][n][r] = e;
                ls += e;
            }
            ls += __shfl_xor(ls, 1, 64);
            ls += __shfl_xor(ls, 2, 64);
            ls += __shfl_xor(ls, 4, 64);
            ls += __shfl_xor(ls, 8, 64);
            if (lrow == 0) rowredS[wave * 64 + m * 16 + lk * 4 + r] = ls;
        }
    __syncthreads();
#pragma unroll
    for (int m = 0; m < 4; ++m)
#pragma unroll
        for (int r = 0; r < 4; ++r) {
            int row = wr * 256 + m * 16 + lk * 4 + r;
            float sum = rowredS[row] + rowredS[64 + row] + rowredS[128 + row] + rowredS[192 + row];
            inv_[m][r] = 1.0f / (sum + 1e-6f);
        }

    // ---- write S1 (f16): two 64-row passes through Bs (swizzled), coalesced writeback ----
    char* Bs2 = (char*)Bs;
#pragma unroll
    for (int p = 0; p < 2; ++p) {
        __syncthreads();
        if (wr == p) {
#pragma unroll
            for (int m = 0; m < 4; ++m)
#pragma unroll
                for (int n = 0; n < 4; ++n)
#pragma unroll
                    for (int r = 0; r < 4; ++r) {
                        int il = m * 16 + lk * 4 + r;
                        int jj = jw + n * 16 + lrow;
                        int byte = il * 512 + (((jj >> 3) ^ (il & 7)) * 16) + (jj & 7) * 2;
                        *(_Float16*)(Bs2 + byte) = (_Float16)(acc[m][n][r] * inv_[m][r]);
                    }
        }
        __syncthreads();
#pragma unroll
        for (int sb = 0; sb < 4; ++sb) {
            int row = sb * 16 + (t >> 5);
            int c = t & 31;
            uint4 v = *(uint4*)(Bs2 + row * 512 + ((c ^ (row & 7)) * 16));
            *(uint4*)(S1h + ((size_t)(b * CL_ + i0 + p * 64 + row)) * QL_ + c * 8) = v;
        }
    }
}

// ---------------- column combine (16 slices) -> s2max -> Bmat ----------------
__global__ void combine_bmat_kernel(const float* __restrict__ pm, const float* __restrict__ ps,
                                    const float* __restrict__ pum, const _Float16* __restrict__ Qh,
                                    float* __restrict__ bmat) {
    __shared__ float sm[QL_];
    int b = blockIdx.x;
    int t = threadIdx.x;
    {
        float m = -1e30f, s = 0.f, um = -1e30f;
        for (int k = 0; k < 16; ++k) {
            int idx = (b * 16 + k) * QL_ + t;
            float mk = pm[idx], sk = ps[idx], umk = pum[idx];
            float nm = fmaxf(m, mk);
            s = s * __expf(m - nm) + sk * __expf(mk - nm);
            m = nm;
            um = fmaxf(um, umk);
        }
        sm[t] = (um < -1e29f) ? 0.0f : __expf(um - m) / (s + 1e-6f);
    }
    __syncthreads();
#pragma unroll
    for (int c = 0; c < 3; ++c) {
        int d = c * 256 + t;
        const _Float16* qb = Qh + (size_t)b * QL_ * D_ + d;
        float s = 0.f;
        for (int j = 0; j < QL_; ++j) s += sm[j] * (float)qb[(size_t)j * D_];
        bmat[b * D_ + d] = s;
    }
}

// ---- A-GEMM (S1 @ Q), 128x128, swapped operands -> float4 epilogue on d ----
__global__ __launch_bounds__(512) void agemm_out_kernel(
    const _Float16* __restrict__ S1h, const _Float16* __restrict__ QTh,
    const float* __restrict__ C, const float* __restrict__ bmat, float* __restrict__ out) {
    __shared__ __align__(16) _Float16 As[128 * 64];   // S1 rows (i)
    __shared__ __align__(16) _Float16 Bs[128 * 64];   // QT rows (d)
    int t  = threadIdx.x;
    int b  = blockIdx.z;
    int d0 = blockIdx.x * 128;
    int i0 = blockIdx.y * 128;
    const _Float16* Sbase = S1h + ((size_t)b * CL_ + i0) * QL_;
    const _Float16* Qbase = QTh + ((size_t)b * D_ + d0) * QL_;
    int wave = t >> 6, lane = t & 63, lrow = lane & 15, lk = lane >> 4;
    int wr = wave >> 1, wc = wave & 1;   // wr: d 32-block (4), wc: i 64-block (2)
    f32x4 acc[2][4] = {};                 // [m: d 16-group][n: i 16-group]
    int srow = t >> 3, sc = t & 7;
    for (int k0 = 0; k0 < QL_; k0 += 64) {
        __syncthreads();
#pragma unroll
        for (int s2 = 0; s2 < 2; ++s2) {
            int row = s2 * 64 + srow;
            int sw = (sc ^ (row & 7)) * 8;
            f16x8 av = *(const f16x8*)(Sbase + (size_t)row * QL_ + k0 + sc * 8);
            f16x8 bv = *(const f16x8*)(Qbase + (size_t)row * QL_ + k0 + sc * 8);
            *(f16x8*)&As[row * 64 + sw] = av;
            *(f16x8*)&Bs[row * 64 + sw] = bv;
        }
        __syncthreads();
#pragma unroll
        for (int kk = 0; kk < 2; ++kk) {
            int slot = kk * 4 + lk;
            int swa = (slot ^ (lrow & 7)) * 8;
            f16x8 qf[2];
#pragma unroll
            for (int m = 0; m < 2; ++m)
                qf[m] = *(const f16x8*)&Bs[(wr * 32 + m * 16 + lrow) * 64 + swa];
#pragma unroll
            for (int n = 0; n < 4; ++n) {
                f16x8 sf = *(const f16x8*)&As[(wc * 64 + n * 16 + lrow) * 64 + swa];
#pragma unroll
                for (int m = 0; m < 2; ++m)
                    acc[m][n] = __builtin_amdgcn_mfma_f32_16x16x32_f16(qf[m], sf, acc[m][n], 0, 0, 0);
            }
        }
    }
    // epilogue: lane holds 4 consecutive d (reg r) for one i per (m,n)
    f32x4 bm4[2];
#pragma unroll
    for (int m = 0; m < 2; ++m)
        bm4[m] = *(const f32x4*)(bmat + b * D_ + d0 + wr * 32 + m * 16 + lk * 4);
#pragma unroll
    for (int n = 0; n < 4; ++n) {
        int i = i0 + wc * 64 + n * 16 + lrow;
        size_t crow = ((size_t)b * CL_ + i) * D_;
        size_t ob = ((size_t)b * CL_ + i) * (size_t)(4 * D_);
#pragma unroll
        for (int m = 0; m < 2; ++m) {
            int d = d0 + wr * 32 + m * 16 + lk * 4;
            f32x4 c4 = *(const f32x4*)(C + crow + d);
            f32x4 a4 = acc[m][n];
            f32x4 ca = c4 * a4;
            f32x4 cb = c4 * bm4[m];
            __builtin_nontemporal_store(c4, (f32x4*)(out + ob + d));
            __builtin_nontemporal_store(a4, (f32x4*)(out + ob + D_ + d));
            __builtin_nontemporal_store(ca, (f32x4*)(out + ob + 2 * D_ + d));
            __builtin_nontemporal_store(cb, (f32x4*)(out + ob + 3 * D_ + d));
        }
    }
}

extern "C" void kernel_launch(void* const* d_in, const int* in_sizes, int n_in,
                              void* d_out, int out_size, void* d_ws, size_t ws_size,
                              hipStream_t stream) {
    const float* C      = (const float*)d_in[0];
    const float* Q      = (const float*)d_in[1];
    const float* w      = (const float*)d_in[2];
    const int*   c_mask = (const int*)d_in[3];
    const int*   q_mask = (const int*)d_in[4];
    float* out = (float*)d_out;
    char* ws = (char*)d_ws;

    // workspace layout (bytes)
    _Float16* S1h   = (_Float16*)(ws);                      // 16,777,216
    _Float16* QTh   = (_Float16*)(ws + 16777216);           // 12,582,912
    _Float16* Qh    = (_Float16*)(ws + 29360128);           // 12,582,912
    float*    qw2   = (float*)(ws + 41943040);              //     32,768
    float*    pm    = (float*)(ws + 41975808);              //    524,288
    float*    ps    = (float*)(ws + 42500096);              //    524,288
    float*    pum   = (float*)(ws + 43024384);              //    524,288
    float*    bmat  = (float*)(ws + 43581440);              //     98,304

    rowdot_kernel<<<dim3((B_ * QL_) / 4), 256, 0, stream>>>(Q, w + D_, qw2);
    prep_q_kernel<<<dim3(QL_ / 64, D_ / 64, B_), 256, 0, stream>>>(Q, QTh, Qh);
    fused_s_kernel<<<dim3(CL_ / 128, B_), 512, 0, stream>>>(C, Qh, w, qw2, c_mask, q_mask,
                                                            S1h, pm, ps, pum);
    combine_bmat_kernel<<<dim3(B_), 256, 0, stream>>>(pm, ps, pum, Qh, bmat);
    agemm_out_kernel<<<dim3(D_ / 128, CL_ / 128, B_), 512, 0, stream>>>(S1h, QTh, C, bmat, out);
}

// Round 5
// 194.014 us; speedup vs baseline: 1.2220x; 1.2220x over previous
//
#include <hip/hip_runtime.h>

#define B_  32
#define CL_ 1024
#define QL_ 256
#define D_  768

typedef _Float16 f16x8 __attribute__((ext_vector_type(8)));
typedef float    f32x4 __attribute__((ext_vector_type(4)));

// ---------------- rowdot: out[row] = dot(X[row,:], w[:]) over D=768 ----------------
__global__ void rowdot_kernel(const float* __restrict__ X, const float* __restrict__ w,
                              float* __restrict__ out) {
    int wave = threadIdx.x >> 6;
    int lane = threadIdx.x & 63;
    int row  = blockIdx.x * 4 + wave;
    const float* x = X + (size_t)row * D_;
    float s = 0.f;
#pragma unroll
    for (int k = 0; k < D_ / 64; ++k) s += x[lane + k * 64] * w[lane + k * 64];
#pragma unroll
    for (int m = 32; m; m >>= 1) s += __shfl_xor(s, m, 64);
    if (lane == 0) out[row] = s;
}

// ---------------- prep Q: QT[b][d][j] f16 and Qh[b][j][d] f16 (vectorized) ----------------
__global__ __launch_bounds__(256) void prep_q_kernel(const float* __restrict__ Q,
                                                     _Float16* __restrict__ QT,
                                                     _Float16* __restrict__ Qh) {
    __shared__ float tile[64][65];
    int b  = blockIdx.z;
    int j0 = blockIdx.x * 64;
    int d0 = blockIdx.y * 64;
    int t  = threadIdx.x;
    int jj = t >> 4;          // 0..15
    int dd = (t & 15) * 4;    // 0..60
#pragma unroll
    for (int p = 0; p < 4; ++p) {
        int j = jj + p * 16;
        f32x4 v = *(const f32x4*)(Q + ((size_t)b * QL_ + j0 + j) * D_ + d0 + dd);
        *(f32x4*)&tile[j][dd] = v;
        _Float16 h[4] = {(_Float16)v[0], (_Float16)v[1], (_Float16)v[2], (_Float16)v[3]};
        *(uint2*)(Qh + ((size_t)b * QL_ + j0 + j) * D_ + d0 + dd) = *(uint2*)h;
    }
    __syncthreads();
    int j4 = (t & 15) * 4;
#pragma unroll
    for (int p = 0; p < 4; ++p) {
        int d = jj + p * 16;
        _Float16 h[4];
#pragma unroll
        for (int e = 0; e < 4; ++e) h[e] = (_Float16)tile[j4 + e][d];
        *(uint2*)(QT + ((size_t)b * D_ + d0 + d) * QL_ + j0 + j4) = *(uint2*)h;
    }
}

// ---- fused: S-GEMM (128 x 256) + cw1 + row softmax -> S1h + col partial stats ----
__global__ __launch_bounds__(512, 2) void fused_s_kernel(
    const float* __restrict__ C, const _Float16* __restrict__ Qh,
    const float* __restrict__ w, const float* __restrict__ qw2g,
    const int* __restrict__ c_mask, const int* __restrict__ q_mask,
    _Float16* __restrict__ S1h, float* __restrict__ pmg,
    float* __restrict__ psg, float* __restrict__ pumg) {
    __shared__ __align__(16) _Float16 As[128 * 64];
    __shared__ __align__(16) _Float16 Bs[256 * 64];
    __shared__ float w1s[D_], w3s[D_];
    __shared__ float cw1s[128];
    __shared__ float rowredM[512], rowredS[512];
    __shared__ int   cms[128], qms[256];

    int t = threadIdx.x;
    int slice = blockIdx.x;      // 0..7
    int b = blockIdx.y;
    int i0 = slice * 128;
    int wave = t >> 6, lane = t & 63, lrow = lane & 15, lk = lane >> 4;
    int wr = wave >> 2, wc = wave & 3;
    int jw = wc * 64;

    for (int k = t; k < D_; k += 512) { w1s[k] = w[k]; w3s[k] = w[2 * D_ + k]; }
    if (t < 128) cms[t] = c_mask[b * CL_ + i0 + t];
    if (t < 256) qms[t] = q_mask[b * QL_ + t];

    const float* Cbase = C + ((size_t)b * CL_ + i0) * D_;
    const _Float16* Qbase = Qh + (size_t)b * QL_ * D_;

    f32x4 acc[4][4] = {};
    float cwp0 = 0.f, cwp1 = 0.f;
    int arow0 = t >> 3, arow1 = 64 + (t >> 3);
    int asc = t & 7;

    for (int k0 = 0; k0 < D_; k0 += 64) {
        __syncthreads();
        {
            int kk0 = k0 + asc * 8;
            float4 w30 = *(const float4*)(&w3s[kk0]);
            float4 w31 = *(const float4*)(&w3s[kk0 + 4]);
            float4 w10 = *(const float4*)(&w1s[kk0]);
            float4 w11 = *(const float4*)(&w1s[kk0 + 4]);
            const float* src0 = Cbase + (size_t)arow0 * D_ + kk0;
            float4 a0 = *(const float4*)src0;
            float4 a1 = *(const float4*)(src0 + 4);
            f16x8 ah;
            ah[0] = (_Float16)(a0.x * w30.x); ah[1] = (_Float16)(a0.y * w30.y);
            ah[2] = (_Float16)(a0.z * w30.z); ah[3] = (_Float16)(a0.w * w30.w);
            ah[4] = (_Float16)(a1.x * w31.x); ah[5] = (_Float16)(a1.y * w31.y);
            ah[6] = (_Float16)(a1.z * w31.z); ah[7] = (_Float16)(a1.w * w31.w);
            cwp0 += a0.x * w10.x + a0.y * w10.y + a0.z * w10.z + a0.w * w10.w
                  + a1.x * w11.x + a1.y * w11.y + a1.z * w11.z + a1.w * w11.w;
            *(f16x8*)&As[arow0 * 64 + ((asc ^ (arow0 & 7)) * 8)] = ah;
            const float* src1 = Cbase + (size_t)arow1 * D_ + kk0;
            float4 b0 = *(const float4*)src1;
            float4 b1 = *(const float4*)(src1 + 4);
            f16x8 bh;
            bh[0] = (_Float16)(b0.x * w30.x); bh[1] = (_Float16)(b0.y * w30.y);
            bh[2] = (_Float16)(b0.z * w30.z); bh[3] = (_Float16)(b0.w * w30.w);
            bh[4] = (_Float16)(b1.x * w31.x); bh[5] = (_Float16)(b1.y * w31.y);
            bh[6] = (_Float16)(b1.z * w31.z); bh[7] = (_Float16)(b1.w * w31.w);
            cwp1 += b0.x * w10.x + b0.y * w10.y + b0.z * w10.z + b0.w * w10.w
                  + b1.x * w11.x + b1.y * w11.y + b1.z * w11.z + b1.w * w11.w;
            *(f16x8*)&As[arow1 * 64 + ((asc ^ (arow1 & 7)) * 8)] = bh;
        }
#pragma unroll
        for (int sb = 0; sb < 4; ++sb) {
            int row = sb * 64 + (t >> 3);
            f16x8 bh = *(const f16x8*)(Qbase + (size_t)row * D_ + k0 + asc * 8);
            *(f16x8*)&Bs[row * 64 + ((asc ^ (row & 7)) * 8)] = bh;
        }
        __syncthreads();
#pragma unroll
        for (int kk = 0; kk < 2; ++kk) {
            int slot = kk * 4 + lk;
            int swa = (slot ^ (lrow & 7)) * 8;
            f16x8 af[4];
#pragma unroll
            for (int m = 0; m < 4; ++m)
                af[m] = *(const f16x8*)&As[(wr * 64 + m * 16 + lrow) * 64 + swa];
#pragma unroll
            for (int n = 0; n < 4; ++n) {
                int rb = jw + n * 16 + lrow;
                f16x8 bf = *(const f16x8*)&Bs[rb * 64 + swa];
#pragma unroll
                for (int m = 0; m < 4; ++m)
                    acc[m][n] = __builtin_amdgcn_mfma_f32_16x16x32_f16(af[m], bf, acc[m][n], 0, 0, 0);
            }
        }
    }

    // ---- cw1 reduction ----
    cwp0 += __shfl_xor(cwp0, 1, 64); cwp0 += __shfl_xor(cwp0, 2, 64); cwp0 += __shfl_xor(cwp0, 4, 64);
    cwp1 += __shfl_xor(cwp1, 1, 64); cwp1 += __shfl_xor(cwp1, 2, 64); cwp1 += __shfl_xor(cwp1, 4, 64);
    if ((t & 7) == 0) { cw1s[arow0] = cwp0; cw1s[arow1] = cwp1; }
    __syncthreads();

    // ---- S = clip(acc + cw1 + qw2) ----
    float qwv[4]; int qmv[4];
#pragma unroll
    for (int n = 0; n < 4; ++n) {
        int j = jw + n * 16 + lrow;
        qwv[n] = qw2g[b * QL_ + j];
        qmv[n] = qms[j];
    }
#pragma unroll
    for (int m = 0; m < 4; ++m) {
#pragma unroll
        for (int r = 0; r < 4; ++r) {
            float cw = cw1s[wr * 64 + m * 16 + lk * 4 + r];
#pragma unroll
            for (int n = 0; n < 4; ++n) {
                float v = acc[m][n][r] + cw + qwv[n];
                acc[m][n][r] = fminf(15.f, fmaxf(-15.f, v));
            }
        }
    }

    // ---- column partial stats ----
    {
        float pmv[4], psv[4], pumv[4];
#pragma unroll
        for (int n = 0; n < 4; ++n) {
            float pmax = -1e30f, umax = -1e30f;
#pragma unroll
            for (int m = 0; m < 4; ++m)
#pragma unroll
                for (int r = 0; r < 4; ++r) {
                    int cm = cms[wr * 64 + m * 16 + lk * 4 + r];
                    float v = acc[m][n][r];
                    pmax = fmaxf(pmax, cm ? v : 0.0f);
                    umax = fmaxf(umax, cm ? v : -1e30f);
                }
            float s = 0.f;
#pragma unroll
            for (int m = 0; m < 4; ++m)
#pragma unroll
                for (int r = 0; r < 4; ++r) {
                    int cm = cms[wr * 64 + m * 16 + lk * 4 + r];
                    s += cm ? __expf(acc[m][n][r] - pmax) : 0.0f;
                }
            pmv[n] = pmax; psv[n] = s; pumv[n] = umax;
        }
#pragma unroll
        for (int off = 16; off <= 32; off <<= 1) {
#pragma unroll
            for (int n = 0; n < 4; ++n) {
                float om = __shfl_xor(pmv[n], off, 64);
                float os = __shfl_xor(psv[n], off, 64);
                float ou = __shfl_xor(pumv[n], off, 64);
                float nm = fmaxf(pmv[n], om);
                psv[n] = psv[n] * __expf(pmv[n] - nm) + os * __expf(om - nm);
                pmv[n] = nm;
                pumv[n] = fmaxf(pumv[n], ou);
            }
        }
        if (lk == 0) {
#pragma unroll
            for (int n = 0; n < 4; ++n) {
                int idx = (b * 16 + slice * 2 + wr) * QL_ + jw + n * 16 + lrow;
                pmg[idx] = pmv[n]; psg[idx] = psv[n]; pumg[idx] = pumv[n];
            }
        }
    }

    // ---- row softmax ----
    float Mv[4][4];
#pragma unroll
    for (int m = 0; m < 4; ++m)
#pragma unroll
        for (int r = 0; r < 4; ++r) {
            float lm = qmv[0] ? acc[m][0][r] : 0.0f;
#pragma unroll
            for (int n = 1; n < 4; ++n) lm = fmaxf(lm, qmv[n] ? acc[m][n][r] : 0.0f);
            lm = fmaxf(lm, __shfl_xor(lm, 1, 64));
            lm = fmaxf(lm, __shfl_xor(lm, 2, 64));
            lm = fmaxf(lm, __shfl_xor(lm, 4, 64));
            lm = fmaxf(lm, __shfl_xor(lm, 8, 64));
            Mv[m][r] = lm;
        }
    if (lrow == 0) {
#pragma unroll
        for (int m = 0; m < 4; ++m)
#pragma unroll
            for (int r = 0; r < 4; ++r)
                rowredM[wave * 64 + m * 16 + lk * 4 + r] = Mv[m][r];
    }
    __syncthreads();
#pragma unroll
    for (int m = 0; m < 4; ++m)
#pragma unroll
        for (int r = 0; r < 4; ++r) {
            int row = wr * 256 + m * 16 + lk * 4 + r;
            Mv[m][r] = fmaxf(fmaxf(rowredM[row], rowredM[64 + row]),
                             fmaxf(rowredM[128 + row], rowredM[192 + row]));
        }
    float inv_[4][4];
#pragma unroll
    for (int m = 0; m < 4; ++m)
#pragma unroll
        for (int r = 0; r < 4; ++r) {
            float ls = 0.f;
#pragma unroll
            for (int n = 0; n < 4; ++n) {
                float e = qmv[n] ? __expf(acc[m][n][r] - Mv[m][r]) : 0.0f;
                acc[m][n][r] = e;
                ls += e;
            }
            ls += __shfl_xor(ls, 1, 64);
            ls += __shfl_xor(ls, 2, 64);
            ls += __shfl_xor(ls, 4, 64);
            ls += __shfl_xor(ls, 8, 64);
            if (lrow == 0) rowredS[wave * 64 + m * 16 + lk * 4 + r] = ls;
        }
    __syncthreads();
#pragma unroll
    for (int m = 0; m < 4; ++m)
#pragma unroll
        for (int r = 0; r < 4; ++r) {
            int row = wr * 256 + m * 16 + lk * 4 + r;
            float sum = rowredS[row] + rowredS[64 + row] + rowredS[128 + row] + rowredS[192 + row];
            inv_[m][r] = 1.0f / (sum + 1e-6f);
        }

    // ---- write S1 (f16): two 64-row passes through Bs (swizzled), coalesced writeback ----
    char* Bs2 = (char*)Bs;
#pragma unroll
    for (int p = 0; p < 2; ++p) {
        __syncthreads();
        if (wr == p) {
#pragma unroll
            for (int m = 0; m < 4; ++m)
#pragma unroll
                for (int n = 0; n < 4; ++n)
#pragma unroll
                    for (int r = 0; r < 4; ++r) {
                        int il = m * 16 + lk * 4 + r;
                        int jj = jw + n * 16 + lrow;
                        int byte = il * 512 + (((jj >> 3) ^ (il & 7)) * 16) + (jj & 7) * 2;
                        *(_Float16*)(Bs2 + byte) = (_Float16)(acc[m][n][r] * inv_[m][r]);
                    }
        }
        __syncthreads();
#pragma unroll
        for (int sb = 0; sb < 4; ++sb) {
            int row = sb * 16 + (t >> 5);
            int c = t & 31;
            uint4 v = *(uint4*)(Bs2 + row * 512 + ((c ^ (row & 7)) * 16));
            *(uint4*)(S1h + ((size_t)(b * CL_ + i0 + p * 64 + row)) * QL_ + c * 8) = v;
        }
    }
}

// ---------------- column combine (16 slices) -> s2max -> Bmat ----------------
__global__ void combine_bmat_kernel(const float* __restrict__ pm, const float* __restrict__ ps,
                                    const float* __restrict__ pum, const _Float16* __restrict__ Qh,
                                    float* __restrict__ bmat) {
    __shared__ float sm[QL_];
    int b = blockIdx.x;
    int t = threadIdx.x;
    {
        float m = -1e30f, s = 0.f, um = -1e30f;
        for (int k = 0; k < 16; ++k) {
            int idx = (b * 16 + k) * QL_ + t;
            float mk = pm[idx], sk = ps[idx], umk = pum[idx];
            float nm = fmaxf(m, mk);
            s = s * __expf(m - nm) + sk * __expf(mk - nm);
            m = nm;
            um = fmaxf(um, umk);
        }
        sm[t] = (um < -1e29f) ? 0.0f : __expf(um - m) / (s + 1e-6f);
    }
    __syncthreads();
#pragma unroll
    for (int c = 0; c < 3; ++c) {
        int d = c * 256 + t;
        const _Float16* qb = Qh + (size_t)b * QL_ * D_ + d;
        float s = 0.f;
        for (int j = 0; j < QL_; ++j) s += sm[j] * (float)qb[(size_t)j * D_];
        bmat[b * D_ + d] = s;
    }
}

// ---- A-GEMM (S1 @ Q), 128x128, swapped operands; LDS-staged coalesced epilogue ----
__global__ __launch_bounds__(512) void agemm_out_kernel(
    const _Float16* __restrict__ S1h, const _Float16* __restrict__ QTh,
    const float* __restrict__ C, const float* __restrict__ bmat, float* __restrict__ out) {
    __shared__ __align__(16) _Float16 As[128 * 64];   // S1 rows (i)
    __shared__ __align__(16) _Float16 Bs[128 * 64];   // QT rows (d)
    __shared__ __align__(16) float fbuf[64 * 132];    // 64 i-rows x 128 d (pad 4)
    int t  = threadIdx.x;
    int b  = blockIdx.z;
    int d0 = blockIdx.x * 128;
    int i0 = blockIdx.y * 128;
    const _Float16* Sbase = S1h + ((size_t)b * CL_ + i0) * QL_;
    const _Float16* Qbase = QTh + ((size_t)b * D_ + d0) * QL_;
    int wave = t >> 6, lane = t & 63, lrow = lane & 15, lk = lane >> 4;
    int wr = wave >> 1, wc = wave & 1;   // wr: d 32-block (4), wc: i 64-block (2)
    f32x4 acc[2][4] = {};                 // [m: d 16-group][n: i 16-group]
    int srow = t >> 3, sc = t & 7;
    for (int k0 = 0; k0 < QL_; k0 += 64) {
        __syncthreads();
#pragma unroll
        for (int s2 = 0; s2 < 2; ++s2) {
            int row = s2 * 64 + srow;
            int sw = (sc ^ (row & 7)) * 8;
            f16x8 av = *(const f16x8*)(Sbase + (size_t)row * QL_ + k0 + sc * 8);
            f16x8 bv = *(const f16x8*)(Qbase + (size_t)row * QL_ + k0 + sc * 8);
            *(f16x8*)&As[row * 64 + sw] = av;
            *(f16x8*)&Bs[row * 64 + sw] = bv;
        }
        __syncthreads();
#pragma unroll
        for (int kk = 0; kk < 2; ++kk) {
            int slot = kk * 4 + lk;
            int swa = (slot ^ (lrow & 7)) * 8;
            f16x8 qf[2];
#pragma unroll
            for (int m = 0; m < 2; ++m)
                qf[m] = *(const f16x8*)&Bs[(wr * 32 + m * 16 + lrow) * 64 + swa];
#pragma unroll
            for (int n = 0; n < 4; ++n) {
                f16x8 sf = *(const f16x8*)&As[(wc * 64 + n * 16 + lrow) * 64 + swa];
#pragma unroll
                for (int m = 0; m < 2; ++m)
                    acc[m][n] = __builtin_amdgcn_mfma_f32_16x16x32_f16(qf[m], sf, acc[m][n], 0, 0, 0);
            }
        }
    }
    // acc[m][n][r]: d = d0 + wr*32 + m*16 + lk*4 + r ; i = i0 + wc*64 + n*16 + lrow
    // Stage 64 i-rows at a time into fbuf, then fully-coalesced writeback (512B runs).
    int c32 = t & 31;                 // d-quad index in writeback
    f32x4 bm4 = *(const f32x4*)(bmat + b * D_ + d0 + c32 * 4);
#pragma unroll
    for (int p = 0; p < 2; ++p) {
        if (wc == p) {
#pragma unroll
            for (int n = 0; n < 4; ++n)
#pragma unroll
                for (int m = 0; m < 2; ++m)
                    *(f32x4*)&fbuf[(n * 16 + lrow) * 132 + wr * 32 + m * 16 + lk * 4] = acc[m][n];
        }
        __syncthreads();
#pragma unroll
        for (int q = 0; q < 4; ++q) {
            int row = q * 16 + (t >> 5);
            int i = i0 + p * 64 + row;
            f32x4 a4 = *(const f32x4*)&fbuf[row * 132 + c32 * 4];
            f32x4 c4 = *(const f32x4*)(C + ((size_t)b * CL_ + i) * D_ + d0 + c32 * 4);
            size_t ob = ((size_t)b * CL_ + i) * (size_t)(4 * D_) + d0 + c32 * 4;
            __builtin_nontemporal_store(c4,       (f32x4*)(out + ob));
            __builtin_nontemporal_store(a4,       (f32x4*)(out + ob + D_));
            __builtin_nontemporal_store(c4 * a4,  (f32x4*)(out + ob + 2 * D_));
            __builtin_nontemporal_store(c4 * bm4, (f32x4*)(out + ob + 3 * D_));
        }
        if (p == 0) __syncthreads();
    }
}

extern "C" void kernel_launch(void* const* d_in, const int* in_sizes, int n_in,
                              void* d_out, int out_size, void* d_ws, size_t ws_size,
                              hipStream_t stream) {
    const float* C      = (const float*)d_in[0];
    const float* Q      = (const float*)d_in[1];
    const float* w      = (const float*)d_in[2];
    const int*   c_mask = (const int*)d_in[3];
    const int*   q_mask = (const int*)d_in[4];
    float* out = (float*)d_out;
    char* ws = (char*)d_ws;

    // workspace layout (bytes)
    _Float16* S1h   = (_Float16*)(ws);                      // 16,777,216
    _Float16* QTh   = (_Float16*)(ws + 16777216);           // 12,582,912
    _Float16* Qh    = (_Float16*)(ws + 29360128);           // 12,582,912
    float*    qw2   = (float*)(ws + 41943040);              //     32,768
    float*    pm    = (float*)(ws + 41975808);              //    524,288
    float*    ps    = (float*)(ws + 42500096);              //    524,288
    float*    pum   = (float*)(ws + 43024384);              //    524,288
    float*    bmat  = (float*)(ws + 43581440);              //     98,304

    rowdot_kernel<<<dim3((B_ * QL_) / 4), 256, 0, stream>>>(Q, w + D_, qw2);
    prep_q_kernel<<<dim3(QL_ / 64, D_ / 64, B_), 256, 0, stream>>>(Q, QTh, Qh);
    fused_s_kernel<<<dim3(CL_ / 128, B_), 512, 0, stream>>>(C, Qh, w, qw2, c_mask, q_mask,
                                                            S1h, pm, ps, pum);
    combine_bmat_kernel<<<dim3(B_), 256, 0, stream>>>(pm, ps, pum, Qh, bmat);
    agemm_out_kernel<<<dim3(D_ / 128, CL_ / 128, B_), 512, 0, stream>>>(S1h, QTh, C, bmat, out);
}

// Round 6
// 177.633 us; speedup vs baseline: 1.3347x; 1.0922x over previous
//
#include <hip/hip_runtime.h>

#define B_  32
#define CL_ 1024
#define QL_ 256
#define D_  768

typedef _Float16 f16x8 __attribute__((ext_vector_type(8)));
typedef float    f32x4 __attribute__((ext_vector_type(4)));

// ---------------- rowdot: out[row] = dot(X[row,:], w[:]) over D=768 ----------------
__global__ void rowdot_kernel(const float* __restrict__ X, const float* __restrict__ w,
                              float* __restrict__ out) {
    int wave = threadIdx.x >> 6;
    int lane = threadIdx.x & 63;
    int row  = blockIdx.x * 4 + wave;
    const float* x = X + (size_t)row * D_;
    float s = 0.f;
#pragma unroll
    for (int k = 0; k < D_ / 64; ++k) s += x[lane + k * 64] * w[lane + k * 64];
#pragma unroll
    for (int m = 32; m; m >>= 1) s += __shfl_xor(s, m, 64);
    if (lane == 0) out[row] = s;
}

// ---------------- prep Q: QT[b][d][j] f16 and Qh[b][j][d] f16 (vectorized) ----------------
__global__ __launch_bounds__(256) void prep_q_kernel(const float* __restrict__ Q,
                                                     _Float16* __restrict__ QT,
                                                     _Float16* __restrict__ Qh) {
    __shared__ float tile[64][65];
    int b  = blockIdx.z;
    int j0 = blockIdx.x * 64;
    int d0 = blockIdx.y * 64;
    int t  = threadIdx.x;
    int jj = t >> 4;          // 0..15
    int dd = (t & 15) * 4;    // 0..60
#pragma unroll
    for (int p = 0; p < 4; ++p) {
        int j = jj + p * 16;
        f32x4 v = *(const f32x4*)(Q + ((size_t)b * QL_ + j0 + j) * D_ + d0 + dd);
        *(f32x4*)&tile[j][dd] = v;
        _Float16 h[4] = {(_Float16)v[0], (_Float16)v[1], (_Float16)v[2], (_Float16)v[3]};
        *(uint2*)(Qh + ((size_t)b * QL_ + j0 + j) * D_ + d0 + dd) = *(uint2*)h;
    }
    __syncthreads();
    int j4 = (t & 15) * 4;
#pragma unroll
    for (int p = 0; p < 4; ++p) {
        int d = jj + p * 16;
        _Float16 h[4];
#pragma unroll
        for (int e = 0; e < 4; ++e) h[e] = (_Float16)tile[j4 + e][d];
        *(uint2*)(QT + ((size_t)b * D_ + d0 + d) * QL_ + j0 + j4) = *(uint2*)h;
    }
}

// ---- fused: S-GEMM (128 x 256) + cw1 + row softmax -> S1h + col partial stats ----
// grid: 256 blocks, bid = slice*32 + b  (XCD = b%8 pins all slices of b to one XCD)
__global__ __launch_bounds__(512, 2) void fused_s_kernel(
    const float* __restrict__ C, const _Float16* __restrict__ Qh,
    const float* __restrict__ w, const float* __restrict__ qw2g,
    const int* __restrict__ c_mask, const int* __restrict__ q_mask,
    _Float16* __restrict__ S1h, float* __restrict__ pmg,
    float* __restrict__ psg, float* __restrict__ pumg) {
    __shared__ __align__(16) _Float16 As[128 * 64];
    __shared__ __align__(16) _Float16 Bs[256 * 64];
    __shared__ float w1s[D_], w3s[D_];
    __shared__ float cw1s[128];
    __shared__ float rowredM[512], rowredS[512];
    __shared__ int   cms[128], qms[256];

    int t = threadIdx.x;
    int bid = blockIdx.x;
    int b = bid & 31;
    int slice = bid >> 5;        // 0..7
    int i0 = slice * 128;
    int wave = t >> 6, lane = t & 63, lrow = lane & 15, lk = lane >> 4;
    int wr = wave >> 2, wc = wave & 3;
    int jw = wc * 64;

    for (int k = t; k < D_; k += 512) { w1s[k] = w[k]; w3s[k] = w[2 * D_ + k]; }
    if (t < 128) cms[t] = c_mask[b * CL_ + i0 + t];
    if (t < 256) qms[t] = q_mask[b * QL_ + t];

    const float* Cbase = C + ((size_t)b * CL_ + i0) * D_;
    const _Float16* Qbase = Qh + (size_t)b * QL_ * D_;

    f32x4 acc[4][4] = {};
    float cwp0 = 0.f, cwp1 = 0.f;
    int arow0 = t >> 3, arow1 = 64 + (t >> 3);
    int asc = t & 7;

    for (int k0 = 0; k0 < D_; k0 += 64) {
        __syncthreads();
        {
            int kk0 = k0 + asc * 8;
            float4 w30 = *(const float4*)(&w3s[kk0]);
            float4 w31 = *(const float4*)(&w3s[kk0 + 4]);
            float4 w10 = *(const float4*)(&w1s[kk0]);
            float4 w11 = *(const float4*)(&w1s[kk0 + 4]);
            const float* src0 = Cbase + (size_t)arow0 * D_ + kk0;
            float4 a0 = *(const float4*)src0;
            float4 a1 = *(const float4*)(src0 + 4);
            f16x8 ah;
            ah[0] = (_Float16)(a0.x * w30.x); ah[1] = (_Float16)(a0.y * w30.y);
            ah[2] = (_Float16)(a0.z * w30.z); ah[3] = (_Float16)(a0.w * w30.w);
            ah[4] = (_Float16)(a1.x * w31.x); ah[5] = (_Float16)(a1.y * w31.y);
            ah[6] = (_Float16)(a1.z * w31.z); ah[7] = (_Float16)(a1.w * w31.w);
            cwp0 += a0.x * w10.x + a0.y * w10.y + a0.z * w10.z + a0.w * w10.w
                  + a1.x * w11.x + a1.y * w11.y + a1.z * w11.z + a1.w * w11.w;
            *(f16x8*)&As[arow0 * 64 + ((asc ^ (arow0 & 7)) * 8)] = ah;
            const float* src1 = Cbase + (size_t)arow1 * D_ + kk0;
            float4 b0 = *(const float4*)src1;
            float4 b1 = *(const float4*)(src1 + 4);
            f16x8 bh;
            bh[0] = (_Float16)(b0.x * w30.x); bh[1] = (_Float16)(b0.y * w30.y);
            bh[2] = (_Float16)(b0.z * w30.z); bh[3] = (_Float16)(b0.w * w30.w);
            bh[4] = (_Float16)(b1.x * w31.x); bh[5] = (_Float16)(b1.y * w31.y);
            bh[6] = (_Float16)(b1.z * w31.z); bh[7] = (_Float16)(b1.w * w31.w);
            cwp1 += b0.x * w10.x + b0.y * w10.y + b0.z * w10.z + b0.w * w10.w
                  + b1.x * w11.x + b1.y * w11.y + b1.z * w11.z + b1.w * w11.w;
            *(f16x8*)&As[arow1 * 64 + ((asc ^ (arow1 & 7)) * 8)] = bh;
        }
#pragma unroll
        for (int sb = 0; sb < 4; ++sb) {
            int row = sb * 64 + (t >> 3);
            f16x8 bh = *(const f16x8*)(Qbase + (size_t)row * D_ + k0 + asc * 8);
            *(f16x8*)&Bs[row * 64 + ((asc ^ (row & 7)) * 8)] = bh;
        }
        __syncthreads();
#pragma unroll
        for (int kk = 0; kk < 2; ++kk) {
            int slot = kk * 4 + lk;
            int swa = (slot ^ (lrow & 7)) * 8;
            f16x8 af[4];
#pragma unroll
            for (int m = 0; m < 4; ++m)
                af[m] = *(const f16x8*)&As[(wr * 64 + m * 16 + lrow) * 64 + swa];
#pragma unroll
            for (int n = 0; n < 4; ++n) {
                int rb = jw + n * 16 + lrow;
                f16x8 bf = *(const f16x8*)&Bs[rb * 64 + swa];
#pragma unroll
                for (int m = 0; m < 4; ++m)
                    acc[m][n] = __builtin_amdgcn_mfma_f32_16x16x32_f16(af[m], bf, acc[m][n], 0, 0, 0);
            }
        }
    }

    // ---- cw1 reduction ----
    cwp0 += __shfl_xor(cwp0, 1, 64); cwp0 += __shfl_xor(cwp0, 2, 64); cwp0 += __shfl_xor(cwp0, 4, 64);
    cwp1 += __shfl_xor(cwp1, 1, 64); cwp1 += __shfl_xor(cwp1, 2, 64); cwp1 += __shfl_xor(cwp1, 4, 64);
    if ((t & 7) == 0) { cw1s[arow0] = cwp0; cw1s[arow1] = cwp1; }
    __syncthreads();

    // ---- S = clip(acc + cw1 + qw2) ----
    float qwv[4]; int qmv[4];
#pragma unroll
    for (int n = 0; n < 4; ++n) {
        int j = jw + n * 16 + lrow;
        qwv[n] = qw2g[b * QL_ + j];
        qmv[n] = qms[j];
    }
#pragma unroll
    for (int m = 0; m < 4; ++m) {
#pragma unroll
        for (int r = 0; r < 4; ++r) {
            float cw = cw1s[wr * 64 + m * 16 + lk * 4 + r];
#pragma unroll
            for (int n = 0; n < 4; ++n) {
                float v = acc[m][n][r] + cw + qwv[n];
                acc[m][n][r] = fminf(15.f, fmaxf(-15.f, v));
            }
        }
    }

    // ---- column partial stats ----
    {
        float pmv[4], psv[4], pumv[4];
#pragma unroll
        for (int n = 0; n < 4; ++n) {
            float pmax = -1e30f, umax = -1e30f;
#pragma unroll
            for (int m = 0; m < 4; ++m)
#pragma unroll
                for (int r = 0; r < 4; ++r) {
                    int cm = cms[wr * 64 + m * 16 + lk * 4 + r];
                    float v = acc[m][n][r];
                    pmax = fmaxf(pmax, cm ? v : 0.0f);
                    umax = fmaxf(umax, cm ? v : -1e30f);
                }
            float s = 0.f;
#pragma unroll
            for (int m = 0; m < 4; ++m)
#pragma unroll
                for (int r = 0; r < 4; ++r) {
                    int cm = cms[wr * 64 + m * 16 + lk * 4 + r];
                    s += cm ? __expf(acc[m][n][r] - pmax) : 0.0f;
                }
            pmv[n] = pmax; psv[n] = s; pumv[n] = umax;
        }
#pragma unroll
        for (int off = 16; off <= 32; off <<= 1) {
#pragma unroll
            for (int n = 0; n < 4; ++n) {
                float om = __shfl_xor(pmv[n], off, 64);
                float os = __shfl_xor(psv[n], off, 64);
                float ou = __shfl_xor(pumv[n], off, 64);
                float nm = fmaxf(pmv[n], om);
                psv[n] = psv[n] * __expf(pmv[n] - nm) + os * __expf(om - nm);
                pmv[n] = nm;
                pumv[n] = fmaxf(pumv[n], ou);
            }
        }
        if (lk == 0) {
#pragma unroll
            for (int n = 0; n < 4; ++n) {
                int idx = (b * 16 + slice * 2 + wr) * QL_ + jw + n * 16 + lrow;
                pmg[idx] = pmv[n]; psg[idx] = psv[n]; pumg[idx] = pumv[n];
            }
        }
    }

    // ---- row softmax ----
    float Mv[4][4];
#pragma unroll
    for (int m = 0; m < 4; ++m)
#pragma unroll
        for (int r = 0; r < 4; ++r) {
            float lm = qmv[0] ? acc[m][0][r] : 0.0f;
#pragma unroll
            for (int n = 1; n < 4; ++n) lm = fmaxf(lm, qmv[n] ? acc[m][n][r] : 0.0f);
            lm = fmaxf(lm, __shfl_xor(lm, 1, 64));
            lm = fmaxf(lm, __shfl_xor(lm, 2, 64));
            lm = fmaxf(lm, __shfl_xor(lm, 4, 64));
            lm = fmaxf(lm, __shfl_xor(lm, 8, 64));
            Mv[m][r] = lm;
        }
    if (lrow == 0) {
#pragma unroll
        for (int m = 0; m < 4; ++m)
#pragma unroll
            for (int r = 0; r < 4; ++r)
                rowredM[wave * 64 + m * 16 + lk * 4 + r] = Mv[m][r];
    }
    __syncthreads();
#pragma unroll
    for (int m = 0; m < 4; ++m)
#pragma unroll
        for (int r = 0; r < 4; ++r) {
            int row = wr * 256 + m * 16 + lk * 4 + r;
            Mv[m][r] = fmaxf(fmaxf(rowredM[row], rowredM[64 + row]),
                             fmaxf(rowredM[128 + row], rowredM[192 + row]));
        }
    float inv_[4][4];
#pragma unroll
    for (int m = 0; m < 4; ++m)
#pragma unroll
        for (int r = 0; r < 4; ++r) {
            float ls = 0.f;
#pragma unroll
            for (int n = 0; n < 4; ++n) {
                float e = qmv[n] ? __expf(acc[m][n][r] - Mv[m][r]) : 0.0f;
                acc[m][n][r] = e;
                ls += e;
            }
            ls += __shfl_xor(ls, 1, 64);
            ls += __shfl_xor(ls, 2, 64);
            ls += __shfl_xor(ls, 4, 64);
            ls += __shfl_xor(ls, 8, 64);
            if (lrow == 0) rowredS[wave * 64 + m * 16 + lk * 4 + r] = ls;
        }
    __syncthreads();
#pragma unroll
    for (int m = 0; m < 4; ++m)
#pragma unroll
        for (int r = 0; r < 4; ++r) {
            int row = wr * 256 + m * 16 + lk * 4 + r;
            float sum = rowredS[row] + rowredS[64 + row] + rowredS[128 + row] + rowredS[192 + row];
            inv_[m][r] = 1.0f / (sum + 1e-6f);
        }

    // ---- write S1 (f16): two 64-row passes through Bs (swizzled), coalesced writeback ----
    char* Bs2 = (char*)Bs;
#pragma unroll
    for (int p = 0; p < 2; ++p) {
        __syncthreads();
        if (wr == p) {
#pragma unroll
            for (int m = 0; m < 4; ++m)
#pragma unroll
                for (int n = 0; n < 4; ++n)
#pragma unroll
                    for (int r = 0; r < 4; ++r) {
                        int il = m * 16 + lk * 4 + r;
                        int jj = jw + n * 16 + lrow;
                        int byte = il * 512 + (((jj >> 3) ^ (il & 7)) * 16) + (jj & 7) * 2;
                        *(_Float16*)(Bs2 + byte) = (_Float16)(acc[m][n][r] * inv_[m][r]);
                    }
        }
        __syncthreads();
#pragma unroll
        for (int sb = 0; sb < 4; ++sb) {
            int row = sb * 16 + (t >> 5);
            int c = t & 31;
            uint4 v = *(uint4*)(Bs2 + row * 512 + ((c ^ (row & 7)) * 16));
            *(uint4*)(S1h + ((size_t)(b * CL_ + i0 + p * 64 + row)) * QL_ + c * 8) = v;
        }
    }
}

// ---------------- column combine (16 slices) -> s2max -> Bmat ----------------
__global__ void combine_bmat_kernel(const float* __restrict__ pm, const float* __restrict__ ps,
                                    const float* __restrict__ pum, const _Float16* __restrict__ Qh,
                                    float* __restrict__ bmat) {
    __shared__ float sm[QL_];
    int b = blockIdx.x;
    int t = threadIdx.x;
    {
        float m = -1e30f, s = 0.f, um = -1e30f;
        for (int k = 0; k < 16; ++k) {
            int idx = (b * 16 + k) * QL_ + t;
            float mk = pm[idx], sk = ps[idx], umk = pum[idx];
            float nm = fmaxf(m, mk);
            s = s * __expf(m - nm) + sk * __expf(mk - nm);
            m = nm;
            um = fmaxf(um, umk);
        }
        sm[t] = (um < -1e29f) ? 0.0f : __expf(um - m) / (s + 1e-6f);
    }
    __syncthreads();
#pragma unroll
    for (int c = 0; c < 3; ++c) {
        int d = c * 256 + t;
        const _Float16* qb = Qh + (size_t)b * QL_ * D_ + d;
        float s = 0.f;
        for (int j = 0; j < QL_; ++j) s += sm[j] * (float)qb[(size_t)j * D_];
        bmat[b * D_ + d] = s;
    }
}

// ---- A-GEMM (S1 @ Q), 128x128, swapped operands; LDS-staged coalesced epilogue ----
// grid: 1536 blocks, bid = tile*32 + b ; tile = itile*6 + dtile (d fastest for S1h L2 reuse)
__global__ __launch_bounds__(512) void agemm_out_kernel(
    const _Float16* __restrict__ S1h, const _Float16* __restrict__ QTh,
    const float* __restrict__ C, const float* __restrict__ bmat, float* __restrict__ out) {
    __shared__ __align__(16) _Float16 As[128 * 64];   // S1 rows (i)
    __shared__ __align__(16) _Float16 Bs[128 * 64];   // QT rows (d)
    __shared__ __align__(16) float fbuf[64 * 132];    // 64 i-rows x 128 d (pad 4)
    int t  = threadIdx.x;
    int bid = blockIdx.x;
    int b = bid & 31;
    int tile = bid >> 5;             // 0..47
    int d0 = (tile % 6) * 128;
    int i0 = (tile / 6) * 128;
    const _Float16* Sbase = S1h + ((size_t)b * CL_ + i0) * QL_;
    const _Float16* Qbase = QTh + ((size_t)b * D_ + d0) * QL_;
    int wave = t >> 6, lane = t & 63, lrow = lane & 15, lk = lane >> 4;
    int wr = wave >> 1, wc = wave & 1;   // wr: d 32-block (4), wc: i 64-block (2)
    f32x4 acc[2][4] = {};                 // [m: d 16-group][n: i 16-group]
    int srow = t >> 3, sc = t & 7;
    for (int k0 = 0; k0 < QL_; k0 += 64) {
        __syncthreads();
#pragma unroll
        for (int s2 = 0; s2 < 2; ++s2) {
            int row = s2 * 64 + srow;
            int sw = (sc ^ (row & 7)) * 8;
            f16x8 av = *(const f16x8*)(Sbase + (size_t)row * QL_ + k0 + sc * 8);
            f16x8 bv = *(const f16x8*)(Qbase + (size_t)row * QL_ + k0 + sc * 8);
            *(f16x8*)&As[row * 64 + sw] = av;
            *(f16x8*)&Bs[row * 64 + sw] = bv;
        }
        __syncthreads();
#pragma unroll
        for (int kk = 0; kk < 2; ++kk) {
            int slot = kk * 4 + lk;
            int swa = (slot ^ (lrow & 7)) * 8;
            f16x8 qf[2];
#pragma unroll
            for (int m = 0; m < 2; ++m)
                qf[m] = *(const f16x8*)&Bs[(wr * 32 + m * 16 + lrow) * 64 + swa];
#pragma unroll
            for (int n = 0; n < 4; ++n) {
                f16x8 sf = *(const f16x8*)&As[(wc * 64 + n * 16 + lrow) * 64 + swa];
#pragma unroll
                for (int m = 0; m < 2; ++m)
                    acc[m][n] = __builtin_amdgcn_mfma_f32_16x16x32_f16(qf[m], sf, acc[m][n], 0, 0, 0);
            }
        }
    }
    // acc[m][n][r]: d = d0 + wr*32 + m*16 + lk*4 + r ; i = i0 + wc*64 + n*16 + lrow
    // Stage 64 i-rows at a time into fbuf, then fully-coalesced writeback (512B runs).
    int c32 = t & 31;                 // d-quad index in writeback
    f32x4 bm4 = *(const f32x4*)(bmat + b * D_ + d0 + c32 * 4);
#pragma unroll
    for (int p = 0; p < 2; ++p) {
        if (wc == p) {
#pragma unroll
            for (int n = 0; n < 4; ++n)
#pragma unroll
                for (int m = 0; m < 2; ++m)
                    *(f32x4*)&fbuf[(n * 16 + lrow) * 132 + wr * 32 + m * 16 + lk * 4] = acc[m][n];
        }
        __syncthreads();
#pragma unroll
        for (int q = 0; q < 4; ++q) {
            int row = q * 16 + (t >> 5);
            int i = i0 + p * 64 + row;
            f32x4 a4 = *(const f32x4*)&fbuf[row * 132 + c32 * 4];
            f32x4 c4 = *(const f32x4*)(C + ((size_t)b * CL_ + i) * D_ + d0 + c32 * 4);
            size_t ob = ((size_t)b * CL_ + i) * (size_t)(4 * D_) + d0 + c32 * 4;
            __builtin_nontemporal_store(c4,       (f32x4*)(out + ob));
            __builtin_nontemporal_store(a4,       (f32x4*)(out + ob + D_));
            __builtin_nontemporal_store(c4 * a4,  (f32x4*)(out + ob + 2 * D_));
            __builtin_nontemporal_store(c4 * bm4, (f32x4*)(out + ob + 3 * D_));
        }
        if (p == 0) __syncthreads();
    }
}

extern "C" void kernel_launch(void* const* d_in, const int* in_sizes, int n_in,
                              void* d_out, int out_size, void* d_ws, size_t ws_size,
                              hipStream_t stream) {
    const float* C      = (const float*)d_in[0];
    const float* Q      = (const float*)d_in[1];
    const float* w      = (const float*)d_in[2];
    const int*   c_mask = (const int*)d_in[3];
    const int*   q_mask = (const int*)d_in[4];
    float* out = (float*)d_out;
    char* ws = (char*)d_ws;

    // workspace layout (bytes)
    _Float16* S1h   = (_Float16*)(ws);                      // 16,777,216
    _Float16* QTh   = (_Float16*)(ws + 16777216);           // 12,582,912
    _Float16* Qh    = (_Float16*)(ws + 29360128);           // 12,582,912
    float*    qw2   = (float*)(ws + 41943040);              //     32,768
    float*    pm    = (float*)(ws + 41975808);              //    524,288
    float*    ps    = (float*)(ws + 42500096);              //    524,288
    float*    pum   = (float*)(ws + 43024384);              //    524,288
    float*    bmat  = (float*)(ws + 43581440);              //     98,304

    rowdot_kernel<<<dim3((B_ * QL_) / 4), 256, 0, stream>>>(Q, w + D_, qw2);
    prep_q_kernel<<<dim3(QL_ / 64, D_ / 64, B_), 256, 0, stream>>>(Q, QTh, Qh);
    fused_s_kernel<<<dim3(256), 512, 0, stream>>>(C, Qh, w, qw2, c_mask, q_mask,
                                                  S1h, pm, ps, pum);
    combine_bmat_kernel<<<dim3(B_), 256, 0, stream>>>(pm, ps, pum, Qh, bmat);
    agemm_out_kernel<<<dim3(1536), 512, 0, stream>>>(S1h, QTh, C, bmat, out);
}